// Round 1
// baseline (1123.433 us; speedup 1.0000x reference)
//
#include <hip/hip_runtime.h>
#include <hip/hip_bf16.h>
#include <math.h>

#define DEV __device__ __forceinline__

typedef __attribute__((ext_vector_type(8))) short short8;   // 8 x bf16 (4 VGPR)
typedef __attribute__((ext_vector_type(4))) float f32x4;    // MFMA accumulator

// fp32 -> bf16 round-to-nearest-even
DEV short f2bf(float f) {
  union { float f; unsigned u; } v; v.f = f;
  unsigned r = v.u + 0x7fffu + ((v.u >> 16) & 1u);
  return (short)(r >> 16);
}

// async global->LDS, 16B per lane. ldsbase must be wave-uniform; HW writes
// ldsbase + lane*16. Global pointer is per-lane.
DEV void gload16(const void* g, void* l) {
  __builtin_amdgcn_global_load_lds(
      (__attribute__((address_space(1))) void*)g,
      (__attribute__((address_space(3))) void*)l, 16, 0, 0);
}

// ---------------- LayerNorm (fp32 in -> bf16 out), one row per block ----------
__global__ __launch_bounds__(256) void ln_kernel(
    const float* __restrict__ x, const float* __restrict__ g,
    const float* __restrict__ b, short* __restrict__ out) {
  int row = blockIdx.x;                       // 4096 rows
  const float* xr = x + (size_t)row * 2048;
  int tid = threadIdx.x;
  float4 a0 = ((const float4*)xr)[tid * 2];
  float4 a1 = ((const float4*)xr)[tid * 2 + 1];
  float s = a0.x + a0.y + a0.z + a0.w + a1.x + a1.y + a1.z + a1.w;
  float q = a0.x*a0.x + a0.y*a0.y + a0.z*a0.z + a0.w*a0.w
          + a1.x*a1.x + a1.y*a1.y + a1.z*a1.z + a1.w*a1.w;
#pragma unroll
  for (int off = 32; off; off >>= 1) { s += __shfl_xor(s, off); q += __shfl_xor(q, off); }
  __shared__ float red[8];
  int w = tid >> 6;
  if ((tid & 63) == 0) { red[w] = s; red[4 + w] = q; }
  __syncthreads();
  s = red[0] + red[1] + red[2] + red[3];
  q = red[4] + red[5] + red[6] + red[7];
  float mean = s * (1.0f / 2048.0f);
  float var  = q * (1.0f / 2048.0f) - mean * mean;
  float rstd = rsqrtf(var + 1e-5f);
  float xv[8] = {a0.x, a0.y, a0.z, a0.w, a1.x, a1.y, a1.z, a1.w};
  short8 o;
#pragma unroll
  for (int j = 0; j < 8; ++j) {
    int col = tid * 8 + j;
    o[j] = f2bf((xv[j] - mean) * rstd * g[col] + b[col]);
  }
  *(short8*)(out + (size_t)row * 2048 + tid * 8) = o;
}

// ------------- weight transpose+convert: W[K][N] fp32 -> Wt[N][K] bf16 --------
__global__ __launch_bounds__(256) void wt_kernel(
    const float* __restrict__ W, short* __restrict__ Wt, int K, int N) {
  __shared__ short tile[64][65];              // +1 pad vs bank conflicts
  int k0 = blockIdx.x * 64, n0 = blockIdx.y * 64;
  int tx = threadIdx.x, ty = threadIdx.y;     // (64,4)
#pragma unroll
  for (int r = 0; r < 16; ++r) {
    int kl = ty + r * 4;
    tile[kl][tx] = f2bf(W[(size_t)(k0 + kl) * N + n0 + tx]);
  }
  __syncthreads();
#pragma unroll
  for (int r = 0; r < 16; ++r) {
    int nl = ty + r * 4;
    Wt[(size_t)(n0 + nl) * K + k0 + tx] = tile[tx][nl];
  }
}

// ---------------- GEMM: C[M][N] = A[M][K](bf16) * Bt[N][K](bf16)^T ------------
// m97-style: 128x128 tile, BK=32, 4 waves (2x2), each wave 64x64 via 4x4
// frags of 16x16x32. global_load_lds staging with pre-swizzled source
// (XOR slot^(row&3)) matching swizzled ds_read_b128 (both-sides swizzle).
// EPI: 0 = QKV (bias q/k/v, q-scale, bf16 out + transposed V), 1 = residual
// fp32 out (Wo / W2), 2 = bias+GELU bf16 out (W1).
template <int EPI>
__global__ __launch_bounds__(256) void gemm_kernel(
    const short* __restrict__ A, const short* __restrict__ Bt, int K, int N,
    const float* __restrict__ bp1, const float* __restrict__ bp2,
    const float* __restrict__ bp3, const float* __restrict__ res,
    short* __restrict__ outb, float* __restrict__ outf, short* __restrict__ vt) {
  __shared__ char As[8192];                   // [128][32] bf16 (swizzled slots)
  __shared__ char Bs[8192];
  int tid = threadIdx.x, lane = tid & 63, w = tid >> 6;
  int wm = w >> 1, wn = w & 1;
  int hi = lane >> 4, lo = lane & 15;
  int bm = blockIdx.y * 128, bn = blockIdx.x * 128;

  // staging: wave w owns chunks 2w, 2w+1 of A and B. chunk=1KB=16 rows x 64B.
  int srow = 2 * w * 16 + (lane >> 2);
  int sslot = lane & 3;
  const short* Ag0 = A  + (size_t)(bm + srow) * K      + (sslot ^ (srow & 3)) * 8;
  const short* Ag1 = A  + (size_t)(bm + srow + 16) * K + (sslot ^ (srow & 3)) * 8;
  const short* Bg0 = Bt + (size_t)(bn + srow) * K      + (sslot ^ (srow & 3)) * 8;
  const short* Bg1 = Bt + (size_t)(bn + srow + 16) * K + (sslot ^ (srow & 3)) * 8;
  char* Al0 = As + 2 * w * 1024;  char* Al1 = Al0 + 1024;
  char* Bl0 = Bs + 2 * w * 1024;  char* Bl1 = Bl0 + 1024;

  // fragment read addresses (loop-invariant, swizzled)
  const char* aRd[4]; const char* bRd[4];
#pragma unroll
  for (int i = 0; i < 4; ++i) {
    int ra = wm * 64 + i * 16 + lo;
    aRd[i] = As + ra * 64 + ((hi ^ (ra & 3)) << 4);
    int rb = wn * 64 + i * 16 + lo;
    bRd[i] = Bs + rb * 64 + ((hi ^ (rb & 3)) << 4);
  }

  f32x4 acc[4][4] = {};

  for (int k0 = 0; k0 < K; k0 += 32) {
    gload16(Ag0 + k0, Al0);
    gload16(Ag1 + k0, Al1);
    gload16(Bg0 + k0, Bl0);
    gload16(Bg1 + k0, Bl1);
    __syncthreads();                          // includes vmcnt(0) drain
    short8 af[4], bf[4];
#pragma unroll
    for (int i = 0; i < 4; ++i) af[i] = *(const short8*)aRd[i];
#pragma unroll
    for (int i = 0; i < 4; ++i) bf[i] = *(const short8*)bRd[i];
#pragma unroll
    for (int mi = 0; mi < 4; ++mi)
#pragma unroll
      for (int ni = 0; ni < 4; ++ni)
        acc[mi][ni] = __builtin_amdgcn_mfma_f32_16x16x32_bf16(af[mi], bf[ni], acc[mi][ni], 0, 0, 0);
    __syncthreads();                          // reads done before next stage
  }

  // epilogue: D row = wm*64+mi*16+hi*4+r, col = wn*64+ni*16+lo
#pragma unroll
  for (int mi = 0; mi < 4; ++mi) {
#pragma unroll
    for (int ni = 0; ni < 4; ++ni) {
      int n = bn + wn * 64 + ni * 16 + lo;
#pragma unroll
      for (int r = 0; r < 4; ++r) {
        int m = bm + wm * 64 + mi * 16 + hi * 4 + r;
        float v = acc[mi][ni][r];
        if (EPI == 0) {
          float bb = (n < 2048) ? bp1[n] : (n < 4096) ? bp2[n - 2048] : bp3[n - 4096];
          v += bb;
          if (n < 2048) v *= 0.08838834764831845f;   // 1/sqrt(128) folded into Q
          outb[(size_t)m * N + n] = f2bf(v);
          if (n >= 4096) {                           // V also stored transposed
            int b_ = m >> 11, s_ = m & 2047, h_ = (n - 4096) >> 7, dk = (n - 4096) & 127;
            vt[((size_t)((b_ * 16 + h_) * 128 + dk) << 11) + s_] = f2bf(v);
          }
        } else if (EPI == 1) {
          outf[(size_t)m * N + n] = res[(size_t)m * N + n] + v + bp1[n];
        } else {
          float t = v + bp1[n];
          outb[(size_t)m * N + n] = f2bf(0.5f * t * (1.0f + erff(t * 0.70710678118654752f)));
        }
      }
    }
  }
}

// ---------------- flash attention, causal ------------------------------------
// grid (16 q-tiles, 32 b*h). block 256 = 4 waves; each wave 32 q-rows.
// Q pre-scaled; K from qkv buffer, V from transposed Vt[b,h,dk,s].
// KV tile 64. P routed through XOR-swizzled LDS (own-wave rows only).
__global__ __launch_bounds__(256) void attn_kernel(
    const short* __restrict__ qkv, const short* __restrict__ vtb,
    short* __restrict__ ctx) {
  __shared__ char Kl[16384];                  // [64 kv][128 dk] bf16, swizzled
  __shared__ char Vl[16384];                  // [128 dk][64 kv] bf16, swizzled
  __shared__ char Pl[16384];                  // [128 q ][64 kv] bf16, swizzled
  int qt = blockIdx.x, bh = blockIdx.y;
  int b = bh >> 4, h = bh & 15;
  int tid = threadIdx.x, lane = tid & 63, w = tid >> 6;
  int hi = lane >> 4, lo = lane & 15;

  // hoist Q fragments to registers (one-time strided global loads)
  short8 qf[2][4];
#pragma unroll
  for (int mi = 0; mi < 2; ++mi)
#pragma unroll
    for (int ks = 0; ks < 4; ++ks) {
      int row = b * 2048 + qt * 128 + w * 32 + mi * 16 + lo;
      int col = h * 128 + ks * 32 + hi * 8;
      qf[mi][ks] = *(const short8*)(qkv + (size_t)row * 6144 + col);
    }

  f32x4 ao[2][8] = {};
  float mst[2][4], lst[2][4];
#pragma unroll
  for (int i = 0; i < 2; ++i)
#pragma unroll
    for (int r = 0; r < 4; ++r) { mst[i][r] = -1e30f; lst[i][r] = 0.f; }

  int nt = 2 * qt + 2;                        // causal: only tiles kv<=q-range
  for (int t = 0; t < nt; ++t) {
    __syncthreads();                          // prev-iter K/V reads done
#pragma unroll
    for (int i = 0; i < 4; ++i) {             // wave w stages chunks w*4+i
      int c = w * 4 + i;
      int kr = c * 4 + (lane >> 4);           // local kv row 0..63
      int dk16 = lo ^ (kr & 7);               // pre-swizzled source
      const short* kg = qkv + (size_t)(b * 2048 + t * 64 + kr) * 6144
                            + 2048 + h * 128 + dk16 * 8;
      gload16(kg, Kl + c * 1024);
      int vr = c * 8 + (lane >> 3);           // dk row 0..127
      int kv16 = (lane & 7) ^ (vr & 7);
      const short* vg = vtb + (size_t)(bh * 128 + vr) * 2048 + t * 64 + kv16 * 8;
      gload16(vg, Vl + c * 1024);
    }
    __syncthreads();

    // S = Q K^T  (per wave: 2x4 frags of 16x16, K-loop over dk)
    f32x4 sc[2][4] = {};
#pragma unroll
    for (int ks = 0; ks < 4; ++ks) {
      short8 kf[4];
#pragma unroll
      for (int ni = 0; ni < 4; ++ni) {
        int r = ni * 16 + lo;
        kf[ni] = *(const short8*)(Kl + r * 256 + (((ks * 4 + hi) ^ (r & 7)) << 4));
      }
#pragma unroll
      for (int mi = 0; mi < 2; ++mi)
#pragma unroll
        for (int ni = 0; ni < 4; ++ni)
          sc[mi][ni] = __builtin_amdgcn_mfma_f32_16x16x32_bf16(qf[mi][ks], kf[ni], sc[mi][ni], 0, 0, 0);
    }

    if (t >= 2 * qt) {                        // diagonal tiles: causal mask
#pragma unroll
      for (int mi = 0; mi < 2; ++mi)
#pragma unroll
        for (int ni = 0; ni < 4; ++ni)
#pragma unroll
          for (int r = 0; r < 4; ++r) {
            int qrow = qt * 128 + w * 32 + mi * 16 + hi * 4 + r;
            int kv = t * 64 + ni * 16 + lo;
            if (kv > qrow) sc[mi][ni][r] = -1e9f;
          }
    }

    // online softmax per row (row = (mi, hi, r); stats shared by 16-lane group)
#pragma unroll
    for (int mi = 0; mi < 2; ++mi)
#pragma unroll
      for (int r = 0; r < 4; ++r) {
        float vm = fmaxf(fmaxf(sc[mi][0][r], sc[mi][1][r]),
                         fmaxf(sc[mi][2][r], sc[mi][3][r]));
#pragma unroll
        for (int off = 8; off; off >>= 1) vm = fmaxf(vm, __shfl_xor(vm, off));
        float mn = fmaxf(mst[mi][r], vm);
        float corr = __expf(mst[mi][r] - mn);
        float ps = 0.f;
#pragma unroll
        for (int ni = 0; ni < 4; ++ni) {
          float p = __expf(sc[mi][ni][r] - mn);
          sc[mi][ni][r] = p; ps += p;
        }
#pragma unroll
        for (int off = 8; off; off >>= 1) ps += __shfl_xor(ps, off);
        lst[mi][r] = lst[mi][r] * corr + ps;
        mst[mi][r] = mn;
#pragma unroll
        for (int ni = 0; ni < 8; ++ni) ao[mi][ni][r] *= corr;
      }

    // P -> LDS (bf16, swizzled). Each wave touches only its own 32 rows,
    // so no barrier needed between write and read (lgkmcnt handles RAW).
#pragma unroll
    for (int mi = 0; mi < 2; ++mi)
#pragma unroll
      for (int ni = 0; ni < 4; ++ni)
#pragma unroll
        for (int r = 0; r < 4; ++r) {
          int rl = w * 32 + mi * 16 + hi * 4 + r;
          int byte = (rl * 128 + (ni * 16 + lo) * 2) ^ ((rl & 7) << 4);
          *(short*)(Pl + byte) = f2bf(sc[mi][ni][r]);
        }

    // O += P V
#pragma unroll
    for (int ks = 0; ks < 2; ++ks) {
      short8 pf[2];
#pragma unroll
      for (int mi = 0; mi < 2; ++mi) {
        int r = w * 32 + mi * 16 + lo;
        pf[mi] = *(const short8*)(Pl + r * 128 + (((ks * 4 + hi) ^ (r & 7)) << 4));
      }
#pragma unroll
      for (int ni = 0; ni < 8; ++ni) {
        int r = ni * 16 + lo;
        short8 vf = *(const short8*)(Vl + r * 128 + (((ks * 4 + hi) ^ (r & 7)) << 4));
#pragma unroll
        for (int mi = 0; mi < 2; ++mi)
          ao[mi][ni] = __builtin_amdgcn_mfma_f32_16x16x32_bf16(pf[mi], vf, ao[mi][ni], 0, 0, 0);
      }
    }
  }

  // normalize + store ctx bf16 [4096][2048]
#pragma unroll
  for (int mi = 0; mi < 2; ++mi)
#pragma unroll
    for (int r = 0; r < 4; ++r) {
      float inv = 1.0f / lst[mi][r];
      int m = b * 2048 + qt * 128 + w * 32 + mi * 16 + hi * 4 + r;
#pragma unroll
      for (int ni = 0; ni < 8; ++ni) {
        int col = h * 128 + ni * 16 + lo;
        ctx[(size_t)m * 2048 + col] = f2bf(ao[mi][ni][r] * inv);
      }
    }
}

// -----------------------------------------------------------------------------
extern "C" void kernel_launch(void* const* d_in, const int* in_sizes, int n_in,
                              void* d_out, int out_size, void* d_ws, size_t ws_size,
                              hipStream_t stream) {
  const float* src = (const float*)d_in[0];
  // d_in[1] = causal mask (structure hardcoded)
  const float* Wq = (const float*)d_in[2];  const float* bq = (const float*)d_in[3];
  const float* Wk = (const float*)d_in[4];  const float* bk = (const float*)d_in[5];
  const float* Wv = (const float*)d_in[6];  const float* bv = (const float*)d_in[7];
  const float* Wo = (const float*)d_in[8];  const float* bo = (const float*)d_in[9];
  const float* g1 = (const float*)d_in[10]; const float* be1 = (const float*)d_in[11];
  const float* g2 = (const float*)d_in[12]; const float* be2 = (const float*)d_in[13];
  const float* W1 = (const float*)d_in[14]; const float* b1 = (const float*)d_in[15];
  const float* W2 = (const float*)d_in[16]; const float* b2 = (const float*)d_in[17];

  // workspace layout (bytes), total 167,772,160:
  //   [0        ) x_ln   bf16 [4096][2048]   16,777,216
  //   [16777216 ) qkv    bf16 [4096][6144]   50,331,648   (h aliases qkv+vt)
  //   [67108864 ) vt     bf16 [32][128][2048]16,777,216
  //   [83886080 ) ctx    bf16 [4096][2048]   16,777,216
  //   [100663296) xbuf   f32  [4096][2048]   33,554,432
  //   [134217728) wt     bf16 (reused)       33,554,432
  char* ws = (char*)d_ws;
  short* x_ln = (short*)(ws);
  short* qkvb = (short*)(ws + 16777216);
  short* vtb  = (short*)(ws + 67108864);
  short* ctxb = (short*)(ws + 83886080);
  float* xbuf = (float*)(ws + 100663296);
  short* wt   = (short*)(ws + 134217728);
  short* hb   = (short*)(ws + 16777216);      // [4096][8192] bf16, aliases qkv+vt

  dim3 tb(64, 4);

  // QKV weights -> wt rows [0,2048)=Wq^T, [2048,4096)=Wk^T, [4096,6144)=Wv^T
  wt_kernel<<<dim3(32, 32), tb, 0, stream>>>(Wq, wt,                2048, 2048);
  wt_kernel<<<dim3(32, 32), tb, 0, stream>>>(Wk, wt + 2048 * 2048,  2048, 2048);
  wt_kernel<<<dim3(32, 32), tb, 0, stream>>>(Wv, wt + 4096 * 2048,  2048, 2048);
  ln_kernel<<<4096, 256, 0, stream>>>(src, g1, be1, x_ln);
  gemm_kernel<0><<<dim3(48, 32), 256, 0, stream>>>(
      x_ln, wt, 2048, 6144, bq, bk, bv, nullptr, qkvb, nullptr, vtb);
  attn_kernel<<<dim3(16, 32), 256, 0, stream>>>(qkvb, vtb, ctxb);
  wt_kernel<<<dim3(32, 32), tb, 0, stream>>>(Wo, wt, 2048, 2048);
  gemm_kernel<1><<<dim3(16, 32), 256, 0, stream>>>(
      ctxb, wt, 2048, 2048, bo, nullptr, nullptr, src, nullptr, xbuf, nullptr);
  ln_kernel<<<4096, 256, 0, stream>>>(xbuf, g2, be2, x_ln);   // reuse x_ln
  wt_kernel<<<dim3(32, 128), tb, 0, stream>>>(W1, wt, 2048, 8192);
  gemm_kernel<2><<<dim3(64, 32), 256, 0, stream>>>(
      x_ln, wt, 2048, 8192, b1, nullptr, nullptr, nullptr, hb, nullptr, nullptr);
  wt_kernel<<<dim3(128, 32), tb, 0, stream>>>(W2, wt, 8192, 2048);
  gemm_kernel<1><<<dim3(16, 32), 256, 0, stream>>>(
      hb, wt, 8192, 2048, b2, nullptr, nullptr, xbuf, nullptr, (float*)d_out, nullptr);

  (void)in_sizes; (void)n_in; (void)out_size; (void)ws_size;
}

// Round 2
// 985.701 us; speedup vs baseline: 1.1397x; 1.1397x over previous
//
#include <hip/hip_runtime.h>
#include <hip/hip_bf16.h>
#include <math.h>

#define DEV __device__ __forceinline__

typedef __attribute__((ext_vector_type(8))) short short8;   // 8 x bf16 (4 VGPR)
typedef __attribute__((ext_vector_type(4))) float f32x4;    // MFMA accumulator

template<bool B> struct BoolC { static constexpr bool value = B; };

// fp32 -> bf16 round-to-nearest-even
DEV short f2bf(float f) {
  union { float f; unsigned u; } v; v.f = f;
  unsigned r = v.u + 0x7fffu + ((v.u >> 16) & 1u);
  return (short)(r >> 16);
}

// async global->LDS, 16B per lane. LDS base wave-uniform; HW writes base+lane*16.
DEV void gload16(const void* g, void* l) {
  __builtin_amdgcn_global_load_lds(
      (__attribute__((address_space(1))) void*)g,
      (__attribute__((address_space(3))) void*)l, 16, 0, 0);
}

// raw barrier with compiler memory fence (no vmcnt drain — that's the point)
DEV void bar() {
  asm volatile("" ::: "memory");
  __builtin_amdgcn_s_barrier();
  asm volatile("" ::: "memory");
}
template<int N> DEV void vwait() {
  if constexpr (N == 0)      asm volatile("s_waitcnt vmcnt(0)" ::: "memory");
  else if constexpr (N == 3) asm volatile("s_waitcnt vmcnt(3)" ::: "memory");
  else                       asm volatile("s_waitcnt vmcnt(4)" ::: "memory");
}

// ---------------- LayerNorm (fp32 in -> bf16 out), one row per block ----------
__global__ __launch_bounds__(256) void ln_kernel(
    const float* __restrict__ x, const float* __restrict__ g,
    const float* __restrict__ b, short* __restrict__ out) {
  int row = blockIdx.x;                       // 4096 rows
  const float* xr = x + (size_t)row * 2048;
  int tid = threadIdx.x;
  float4 a0 = ((const float4*)xr)[tid * 2];
  float4 a1 = ((const float4*)xr)[tid * 2 + 1];
  float s = a0.x + a0.y + a0.z + a0.w + a1.x + a1.y + a1.z + a1.w;
  float q = a0.x*a0.x + a0.y*a0.y + a0.z*a0.z + a0.w*a0.w
          + a1.x*a1.x + a1.y*a1.y + a1.z*a1.z + a1.w*a1.w;
#pragma unroll
  for (int off = 32; off; off >>= 1) { s += __shfl_xor(s, off); q += __shfl_xor(q, off); }
  __shared__ float red[8];
  int w = tid >> 6;
  if ((tid & 63) == 0) { red[w] = s; red[4 + w] = q; }
  __syncthreads();
  s = red[0] + red[1] + red[2] + red[3];
  q = red[4] + red[5] + red[6] + red[7];
  float mean = s * (1.0f / 2048.0f);
  float var  = q * (1.0f / 2048.0f) - mean * mean;
  float rstd = rsqrtf(var + 1e-5f);
  float xv[8] = {a0.x, a0.y, a0.z, a0.w, a1.x, a1.y, a1.z, a1.w};
  short8 o;
#pragma unroll
  for (int j = 0; j < 8; ++j) {
    int col = tid * 8 + j;
    o[j] = f2bf((xv[j] - mean) * rstd * g[col] + b[col]);
  }
  *(short8*)(out + (size_t)row * 2048 + tid * 8) = o;
}

// ------------- weight transpose+convert: W[K][N] fp32 -> Wt[N][K] bf16 --------
__global__ __launch_bounds__(256) void wt_kernel(
    const float* __restrict__ W, short* __restrict__ Wt, int K, int N) {
  __shared__ short tile[64][65];
  int k0 = blockIdx.x * 64, n0 = blockIdx.y * 64;
  int tx = threadIdx.x, ty = threadIdx.y;     // (64,4)
#pragma unroll
  for (int r = 0; r < 16; ++r) {
    int kl = ty + r * 4;
    tile[kl][tx] = f2bf(W[(size_t)(k0 + kl) * N + n0 + tx]);
  }
  __syncthreads();
#pragma unroll
  for (int r = 0; r < 16; ++r) {
    int nl = ty + r * 4;
    Wt[(size_t)(n0 + nl) * K + k0 + tx] = tile[tx][nl];
  }
}

// ------------- 8-phase GEMM: C[M][N] = A[M][K](bf16) * Bt[N][K](bf16)^T -------
// BN=256 fixed, BK=64 (two K-halves of 32). 512 threads = 8 waves (2m x 4n).
// LDS: ring of 4 K-half slots per matrix (slot g%4 holds global K-half g).
// Tile t reads g=2t,2t+1; stages g=2t+2 (A@ph0, B@ph1), g=2t+3 (A@ph2, B@ph3).
// Counted vmcnt(NW) before barrier at ph1/ph3 end; last tile peeled (vmcnt 0).
// Swizzle: 16B slot ^ ((row>>1)&3), both on pre-swizzled global source and on
// ds_read addr -> <=2-way bank aliasing (free).
// EPI: 0 = QKV (bias, q-scale, bf16 out + transposed V), 1 = residual fp32 out,
// 2 = bias+GELU bf16 out.
template <int BM, int EPI>
__global__ __launch_bounds__(512, 2) void gemm8_kernel(
    const short* __restrict__ A, const short* __restrict__ Bt, int K, int N,
    const float* __restrict__ bp1, const float* __restrict__ bp2,
    const float* __restrict__ bp3, const float* __restrict__ res,
    short* __restrict__ outb, float* __restrict__ outf, short* __restrict__ vt) {
  constexpr int MF  = BM / 32;      // m-frags per wave (8 or 4)
  constexpr int MG  = MF / 2;       // m-frags per phase
  constexpr int SA  = BM * 64;      // A slot bytes ([BM][32] bf16)
  constexpr int SB  = 16384;        // B slot bytes ([256][32] bf16)
  constexpr int CPA = BM / 128;     // A 1KB-chunks per wave per half-stage
  constexpr int CPB = 2;
  constexpr int NW  = CPA + CPB;    // in-flight loads allowed at the wait
  __shared__ char lds[4 * SA + 4 * SB];
  char* Ab = lds;
  char* Bb = lds + 4 * SA;
  int tid = threadIdx.x, lane = tid & 63, w = tid >> 6;
  int wm = w >> 2, wn = w & 3, hi = lane >> 4, lo = lane & 15;
  int bm = blockIdx.y * BM, bn = blockIdx.x * 256;

  // staging: chunk = 16 rows x 64B; lane l -> row c*16+(l>>2), slot l&3 (linear
  // LDS); global source pre-swizzled so LDS slot s holds k-chunk s^((row>>1)&3).
  const char* gA[CPA]; int lA[CPA];
  const char* gB[CPB]; int lB[CPB];
#pragma unroll
  for (int i = 0; i < CPA; ++i) {
    int c = w * CPA + i, r = c * 16 + (lane >> 2);
    gA[i] = (const char*)(A + (size_t)(bm + r) * K) + (((lane & 3) ^ ((r >> 1) & 3)) << 4);
    lA[i] = c * 1024;
  }
#pragma unroll
  for (int i = 0; i < CPB; ++i) {
    int c = w * CPB + i, r = c * 16 + (lane >> 2);
    gB[i] = (const char*)(Bt + (size_t)(bn + r) * K) + (((lane & 3) ^ ((r >> 1) & 3)) << 4);
    lB[i] = c * 1024;
  }
  auto stA = [&](int g) {
    char* d = Ab + (g & 3) * SA;
#pragma unroll
    for (int i = 0; i < CPA; ++i) gload16(gA[i] + (size_t)g * 64, d + lA[i]);
  };
  auto stB = [&](int g) {
    char* d = Bb + (g & 3) * SB;
#pragma unroll
    for (int i = 0; i < CPB; ++i) gload16(gB[i] + (size_t)g * 64, d + lB[i]);
  };

  // fragment read offsets within a slot (swizzled)
  int offA[MF], offB[4];
#pragma unroll
  for (int m = 0; m < MF; ++m) {
    int r = wm * (BM / 2) + m * 16 + lo;
    offA[m] = r * 64 + ((hi ^ ((r >> 1) & 3)) << 4);
  }
#pragma unroll
  for (int n = 0; n < 4; ++n) {
    int r = wn * 64 + n * 16 + lo;
    offB[n] = r * 64 + ((hi ^ ((r >> 1) & 3)) << 4);
  }

  f32x4 acc[MF][4];
#pragma unroll
  for (int m = 0; m < MF; ++m)
#pragma unroll
    for (int n = 0; n < 4; ++n) acc[m][n] = (f32x4){0.f, 0.f, 0.f, 0.f};

  // prologue: stage g=0,1; wait own A0+B0, barrier makes it block-wide
  stA(0); stB(0); stA(1); stB(1);
  vwait<NW>(); bar();

  int NT = K >> 6;
  auto tile = [&](int t, auto stc) {
    constexpr bool ST = decltype(stc)::value;
    char* sa0 = Ab + ((2 * t) & 3) * SA;     char* sb0 = Bb + ((2 * t) & 3) * SB;
    char* sa1 = Ab + ((2 * t + 1) & 3) * SA; char* sb1 = Bb + ((2 * t + 1) & 3) * SB;
    short8 bf[4], af[MG];
    // ---- ph0: mg0 x k0
#pragma unroll
    for (int n = 0; n < 4; ++n) bf[n] = *(const short8*)(sb0 + offB[n]);
#pragma unroll
    for (int m = 0; m < MG; ++m) af[m] = *(const short8*)(sa0 + offA[m]);
    if constexpr (ST) stA(2 * t + 2);
    bar(); __builtin_amdgcn_s_setprio(1);
#pragma unroll
    for (int m = 0; m < MG; ++m)
#pragma unroll
      for (int n = 0; n < 4; ++n)
        acc[m][n] = __builtin_amdgcn_mfma_f32_16x16x32_bf16(af[m], bf[n], acc[m][n], 0, 0, 0);
    __builtin_amdgcn_s_setprio(0); bar();
    // ---- ph1: mg1 x k0 (B frags reused)
#pragma unroll
    for (int m = 0; m < MG; ++m) af[m] = *(const short8*)(sa0 + offA[MG + m]);
    if constexpr (ST) stB(2 * t + 2);
    bar(); __builtin_amdgcn_s_setprio(1);
#pragma unroll
    for (int m = 0; m < MG; ++m)
#pragma unroll
      for (int n = 0; n < 4; ++n)
        acc[MG + m][n] = __builtin_amdgcn_mfma_f32_16x16x32_bf16(af[m], bf[n], acc[MG + m][n], 0, 0, 0);
    __builtin_amdgcn_s_setprio(0);
    if constexpr (ST) vwait<NW>(); else vwait<0>();   // force g=2t+1 landed
    bar();
    // ---- ph2: mg0 x k1
#pragma unroll
    for (int n = 0; n < 4; ++n) bf[n] = *(const short8*)(sb1 + offB[n]);
#pragma unroll
    for (int m = 0; m < MG; ++m) af[m] = *(const short8*)(sa1 + offA[m]);
    if constexpr (ST) stA(2 * t + 3);
    bar(); __builtin_amdgcn_s_setprio(1);
#pragma unroll
    for (int m = 0; m < MG; ++m)
#pragma unroll
      for (int n = 0; n < 4; ++n)
        acc[m][n] = __builtin_amdgcn_mfma_f32_16x16x32_bf16(af[m], bf[n], acc[m][n], 0, 0, 0);
    __builtin_amdgcn_s_setprio(0); bar();
    // ---- ph3: mg1 x k1
#pragma unroll
    for (int m = 0; m < MG; ++m) af[m] = *(const short8*)(sa1 + offA[MG + m]);
    if constexpr (ST) stB(2 * t + 3);
    bar(); __builtin_amdgcn_s_setprio(1);
#pragma unroll
    for (int m = 0; m < MG; ++m)
#pragma unroll
      for (int n = 0; n < 4; ++n)
        acc[MG + m][n] = __builtin_amdgcn_mfma_f32_16x16x32_bf16(af[m], bf[n], acc[MG + m][n], 0, 0, 0);
    __builtin_amdgcn_s_setprio(0);
    if constexpr (ST) vwait<NW>();                    // force g=2t+2 landed
    bar();
  };

  for (int t = 0; t < NT - 1; ++t) tile(t, BoolC<true>{});
  tile(NT - 1, BoolC<false>{});

  // epilogue: row = bm + wm*(BM/2) + mf*16 + hi*4 + r; col = bn + wn*64 + nf*16 + lo
#pragma unroll
  for (int mf = 0; mf < MF; ++mf) {
#pragma unroll
    for (int nf = 0; nf < 4; ++nf) {
      int n = bn + wn * 64 + nf * 16 + lo;
#pragma unroll
      for (int r = 0; r < 4; ++r) {
        int m = bm + wm * (BM / 2) + mf * 16 + hi * 4 + r;
        float v = acc[mf][nf][r];
        if (EPI == 0) {
          float bb = (n < 2048) ? bp1[n] : (n < 4096) ? bp2[n - 2048] : bp3[n - 4096];
          v += bb;
          if (n < 2048) v *= 0.08838834764831845f;   // 1/sqrt(128) folded into Q
          outb[(size_t)m * N + n] = f2bf(v);
          if (n >= 4096) {                           // V also stored transposed
            int b_ = m >> 11, s_ = m & 2047, h_ = (n - 4096) >> 7, dk = (n - 4096) & 127;
            vt[((size_t)((b_ * 16 + h_) * 128 + dk) << 11) + s_] = f2bf(v);
          }
        } else if (EPI == 1) {
          outf[(size_t)m * N + n] = res[(size_t)m * N + n] + v + bp1[n];
        } else {
          float t = v + bp1[n];
          outb[(size_t)m * N + n] = f2bf(0.5f * t * (1.0f + erff(t * 0.70710678118654752f)));
        }
      }
    }
  }
}

// ---------------- flash attention, causal (unchanged this round) --------------
__global__ __launch_bounds__(256) void attn_kernel(
    const short* __restrict__ qkv, const short* __restrict__ vtb,
    short* __restrict__ ctx) {
  __shared__ char Kl[16384];                  // [64 kv][128 dk] bf16, swizzled
  __shared__ char Vl[16384];                  // [128 dk][64 kv] bf16, swizzled
  __shared__ char Pl[16384];                  // [128 q ][64 kv] bf16, swizzled
  int qt = blockIdx.x, bh = blockIdx.y;
  int b = bh >> 4, h = bh & 15;
  int tid = threadIdx.x, lane = tid & 63, w = tid >> 6;
  int hi = lane >> 4, lo = lane & 15;

  short8 qf[2][4];
#pragma unroll
  for (int mi = 0; mi < 2; ++mi)
#pragma unroll
    for (int ks = 0; ks < 4; ++ks) {
      int row = b * 2048 + qt * 128 + w * 32 + mi * 16 + lo;
      int col = h * 128 + ks * 32 + hi * 8;
      qf[mi][ks] = *(const short8*)(qkv + (size_t)row * 6144 + col);
    }

  f32x4 ao[2][8] = {};
  float mst[2][4], lst[2][4];
#pragma unroll
  for (int i = 0; i < 2; ++i)
#pragma unroll
    for (int r = 0; r < 4; ++r) { mst[i][r] = -1e30f; lst[i][r] = 0.f; }

  int nt = 2 * qt + 2;
  for (int t = 0; t < nt; ++t) {
    __syncthreads();
#pragma unroll
    for (int i = 0; i < 4; ++i) {
      int c = w * 4 + i;
      int kr = c * 4 + (lane >> 4);
      int dk16 = lo ^ (kr & 7);
      const short* kg = qkv + (size_t)(b * 2048 + t * 64 + kr) * 6144
                            + 2048 + h * 128 + dk16 * 8;
      gload16(kg, Kl + c * 1024);
      int vr = c * 8 + (lane >> 3);
      int kv16 = (lane & 7) ^ (vr & 7);
      const short* vg = vtb + (size_t)(bh * 128 + vr) * 2048 + t * 64 + kv16 * 8;
      gload16(vg, Vl + c * 1024);
    }
    __syncthreads();

    f32x4 sc[2][4] = {};
#pragma unroll
    for (int ks = 0; ks < 4; ++ks) {
      short8 kf[4];
#pragma unroll
      for (int ni = 0; ni < 4; ++ni) {
        int r = ni * 16 + lo;
        kf[ni] = *(const short8*)(Kl + r * 256 + (((ks * 4 + hi) ^ (r & 7)) << 4));
      }
#pragma unroll
      for (int mi = 0; mi < 2; ++mi)
#pragma unroll
        for (int ni = 0; ni < 4; ++ni)
          sc[mi][ni] = __builtin_amdgcn_mfma_f32_16x16x32_bf16(qf[mi][ks], kf[ni], sc[mi][ni], 0, 0, 0);
    }

    if (t >= 2 * qt) {
#pragma unroll
      for (int mi = 0; mi < 2; ++mi)
#pragma unroll
        for (int ni = 0; ni < 4; ++ni)
#pragma unroll
          for (int r = 0; r < 4; ++r) {
            int qrow = qt * 128 + w * 32 + mi * 16 + hi * 4 + r;
            int kv = t * 64 + ni * 16 + lo;
            if (kv > qrow) sc[mi][ni][r] = -1e9f;
          }
    }

#pragma unroll
    for (int mi = 0; mi < 2; ++mi)
#pragma unroll
      for (int r = 0; r < 4; ++r) {
        float vm = fmaxf(fmaxf(sc[mi][0][r], sc[mi][1][r]),
                         fmaxf(sc[mi][2][r], sc[mi][3][r]));
#pragma unroll
        for (int off = 8; off; off >>= 1) vm = fmaxf(vm, __shfl_xor(vm, off));
        float mn = fmaxf(mst[mi][r], vm);
        float corr = __expf(mst[mi][r] - mn);
        float ps = 0.f;
#pragma unroll
        for (int ni = 0; ni < 4; ++ni) {
          float p = __expf(sc[mi][ni][r] - mn);
          sc[mi][ni][r] = p; ps += p;
        }
#pragma unroll
        for (int off = 8; off; off >>= 1) ps += __shfl_xor(ps, off);
        lst[mi][r] = lst[mi][r] * corr + ps;
        mst[mi][r] = mn;
#pragma unroll
        for (int ni = 0; ni < 8; ++ni) ao[mi][ni][r] *= corr;
      }

#pragma unroll
    for (int mi = 0; mi < 2; ++mi)
#pragma unroll
      for (int ni = 0; ni < 4; ++ni)
#pragma unroll
        for (int r = 0; r < 4; ++r) {
          int rl = w * 32 + mi * 16 + hi * 4 + r;
          int byte = (rl * 128 + (ni * 16 + lo) * 2) ^ ((rl & 7) << 4);
          *(short*)(Pl + byte) = f2bf(sc[mi][ni][r]);
        }

#pragma unroll
    for (int ks = 0; ks < 2; ++ks) {
      short8 pf[2];
#pragma unroll
      for (int mi = 0; mi < 2; ++mi) {
        int r = w * 32 + mi * 16 + lo;
        pf[mi] = *(const short8*)(Pl + r * 128 + (((ks * 4 + hi) ^ (r & 7)) << 4));
      }
#pragma unroll
      for (int ni = 0; ni < 8; ++ni) {
        int r = ni * 16 + lo;
        short8 vf = *(const short8*)(Vl + r * 128 + (((ks * 4 + hi) ^ (r & 7)) << 4));
#pragma unroll
        for (int mi = 0; mi < 2; ++mi)
          ao[mi][ni] = __builtin_amdgcn_mfma_f32_16x16x32_bf16(pf[mi], vf, ao[mi][ni], 0, 0, 0);
      }
    }
  }

#pragma unroll
  for (int mi = 0; mi < 2; ++mi)
#pragma unroll
    for (int r = 0; r < 4; ++r) {
      float inv = 1.0f / lst[mi][r];
      int m = b * 2048 + qt * 128 + w * 32 + mi * 16 + hi * 4 + r;
#pragma unroll
      for (int ni = 0; ni < 8; ++ni) {
        int col = h * 128 + ni * 16 + lo;
        ctx[(size_t)m * 2048 + col] = f2bf(ao[mi][ni][r] * inv);
      }
    }
}

// -----------------------------------------------------------------------------
extern "C" void kernel_launch(void* const* d_in, const int* in_sizes, int n_in,
                              void* d_out, int out_size, void* d_ws, size_t ws_size,
                              hipStream_t stream) {
  const float* src = (const float*)d_in[0];
  const float* Wq = (const float*)d_in[2];  const float* bq = (const float*)d_in[3];
  const float* Wk = (const float*)d_in[4];  const float* bk = (const float*)d_in[5];
  const float* Wv = (const float*)d_in[6];  const float* bv = (const float*)d_in[7];
  const float* Wo = (const float*)d_in[8];  const float* bo = (const float*)d_in[9];
  const float* g1 = (const float*)d_in[10]; const float* be1 = (const float*)d_in[11];
  const float* g2 = (const float*)d_in[12]; const float* be2 = (const float*)d_in[13];
  const float* W1 = (const float*)d_in[14]; const float* b1 = (const float*)d_in[15];
  const float* W2 = (const float*)d_in[16]; const float* b2 = (const float*)d_in[17];

  // workspace layout (bytes), total 167,772,160:
  //   [0        ) x_ln   bf16 [4096][2048]
  //   [16777216 ) qkv    bf16 [4096][6144]   (hb aliases qkv+vt)
  //   [67108864 ) vt     bf16 [32][128][2048]
  //   [83886080 ) ctx    bf16 [4096][2048]
  //   [100663296) xbuf   f32  [4096][2048]
  //   [134217728) wt     bf16 (reused)
  char* ws = (char*)d_ws;
  short* x_ln = (short*)(ws);
  short* qkvb = (short*)(ws + 16777216);
  short* vtb  = (short*)(ws + 67108864);
  short* ctxb = (short*)(ws + 83886080);
  float* xbuf = (float*)(ws + 100663296);
  short* wt   = (short*)(ws + 134217728);
  short* hb   = (short*)(ws + 16777216);

  dim3 tb(64, 4);

  wt_kernel<<<dim3(32, 32), tb, 0, stream>>>(Wq, wt,                2048, 2048);
  wt_kernel<<<dim3(32, 32), tb, 0, stream>>>(Wk, wt + 2048 * 2048,  2048, 2048);
  wt_kernel<<<dim3(32, 32), tb, 0, stream>>>(Wv, wt + 4096 * 2048,  2048, 2048);
  ln_kernel<<<4096, 256, 0, stream>>>(src, g1, be1, x_ln);
  gemm8_kernel<256, 0><<<dim3(24, 16), 512, 0, stream>>>(
      x_ln, wt, 2048, 6144, bq, bk, bv, nullptr, qkvb, nullptr, vtb);
  attn_kernel<<<dim3(16, 32), 256, 0, stream>>>(qkvb, vtb, ctxb);
  wt_kernel<<<dim3(32, 32), tb, 0, stream>>>(Wo, wt, 2048, 2048);
  gemm8_kernel<128, 1><<<dim3(8, 32), 512, 0, stream>>>(
      ctxb, wt, 2048, 2048, bo, nullptr, nullptr, src, nullptr, xbuf, nullptr);
  ln_kernel<<<4096, 256, 0, stream>>>(xbuf, g2, be2, x_ln);
  wt_kernel<<<dim3(32, 128), tb, 0, stream>>>(W1, wt, 2048, 8192);
  gemm8_kernel<256, 2><<<dim3(32, 16), 512, 0, stream>>>(
      x_ln, wt, 2048, 8192, b1, nullptr, nullptr, nullptr, hb, nullptr, nullptr);
  wt_kernel<<<dim3(128, 32), tb, 0, stream>>>(W2, wt, 8192, 2048);
  gemm8_kernel<128, 1><<<dim3(8, 32), 512, 0, stream>>>(
      hb, wt, 8192, 2048, b2, nullptr, nullptr, xbuf, nullptr, (float*)d_out, nullptr);

  (void)in_sizes; (void)n_in; (void)out_size; (void)ws_size;
}

// Round 3
// 920.554 us; speedup vs baseline: 1.2204x; 1.0708x over previous
//
#include <hip/hip_runtime.h>
#include <hip/hip_bf16.h>
#include <math.h>

#define DEV __device__ __forceinline__

typedef __attribute__((ext_vector_type(8))) short short8;   // 8 x bf16 (4 VGPR)
typedef __attribute__((ext_vector_type(4))) float f32x4;    // MFMA accumulator

template<bool B> struct BoolC { static constexpr bool value = B; };

// fp32 -> bf16 round-to-nearest-even
DEV short f2bf(float f) {
  union { float f; unsigned u; } v; v.f = f;
  unsigned r = v.u + 0x7fffu + ((v.u >> 16) & 1u);
  return (short)(r >> 16);
}

// async global->LDS, 16B per lane. LDS base wave-uniform; HW writes base+lane*16.
DEV void gload16(const void* g, void* l) {
  __builtin_amdgcn_global_load_lds(
      (__attribute__((address_space(1))) void*)g,
      (__attribute__((address_space(3))) void*)l, 16, 0, 0);
}

// raw barrier with compiler memory fence (no vmcnt drain — that's the point)
DEV void bar() {
  asm volatile("" ::: "memory");
  __builtin_amdgcn_s_barrier();
  asm volatile("" ::: "memory");
}
template<int N> DEV void vwait() {
  if constexpr (N == 0)      asm volatile("s_waitcnt vmcnt(0)" ::: "memory");
  else if constexpr (N == 3) asm volatile("s_waitcnt vmcnt(3)" ::: "memory");
  else                       asm volatile("s_waitcnt vmcnt(4)" ::: "memory");
}

// ---------------- LayerNorm (fp32 in -> bf16 out), one row per block ----------
__global__ __launch_bounds__(256) void ln_kernel(
    const float* __restrict__ x, const float* __restrict__ g,
    const float* __restrict__ b, short* __restrict__ out) {
  int row = blockIdx.x;                       // 4096 rows
  const float* xr = x + (size_t)row * 2048;
  int tid = threadIdx.x;
  float4 a0 = ((const float4*)xr)[tid * 2];
  float4 a1 = ((const float4*)xr)[tid * 2 + 1];
  float s = a0.x + a0.y + a0.z + a0.w + a1.x + a1.y + a1.z + a1.w;
  float q = a0.x*a0.x + a0.y*a0.y + a0.z*a0.z + a0.w*a0.w
          + a1.x*a1.x + a1.y*a1.y + a1.z*a1.z + a1.w*a1.w;
#pragma unroll
  for (int off = 32; off; off >>= 1) { s += __shfl_xor(s, off); q += __shfl_xor(q, off); }
  __shared__ float red[8];
  int w = tid >> 6;
  if ((tid & 63) == 0) { red[w] = s; red[4 + w] = q; }
  __syncthreads();
  s = red[0] + red[1] + red[2] + red[3];
  q = red[4] + red[5] + red[6] + red[7];
  float mean = s * (1.0f / 2048.0f);
  float var  = q * (1.0f / 2048.0f) - mean * mean;
  float rstd = rsqrtf(var + 1e-5f);
  float xv[8] = {a0.x, a0.y, a0.z, a0.w, a1.x, a1.y, a1.z, a1.w};
  short8 o;
#pragma unroll
  for (int j = 0; j < 8; ++j) {
    int col = tid * 8 + j;
    o[j] = f2bf((xv[j] - mean) * rstd * g[col] + b[col]);
  }
  *(short8*)(out + (size_t)row * 2048 + tid * 8) = o;
}

// ------------- weight transpose+convert: W[K][N] fp32 -> Wt[N][K] bf16 --------
__global__ __launch_bounds__(256) void wt_kernel(
    const float* __restrict__ W, short* __restrict__ Wt, int K, int N) {
  __shared__ short tile[64][65];
  int k0 = blockIdx.x * 64, n0 = blockIdx.y * 64;
  int tx = threadIdx.x, ty = threadIdx.y;     // (64,4)
#pragma unroll
  for (int r = 0; r < 16; ++r) {
    int kl = ty + r * 4;
    tile[kl][tx] = f2bf(W[(size_t)(k0 + kl) * N + n0 + tx]);
  }
  __syncthreads();
#pragma unroll
  for (int r = 0; r < 16; ++r) {
    int nl = ty + r * 4;
    Wt[(size_t)(n0 + nl) * K + k0 + tx] = tile[tx][nl];
  }
}

// ------------- 8-phase GEMM: C[M][N] = A[M][K](bf16) * Bt[N][K](bf16)^T -------
// (unchanged from round 2 — see that round's notes)
template <int BM, int EPI>
__global__ __launch_bounds__(512, 2) void gemm8_kernel(
    const short* __restrict__ A, const short* __restrict__ Bt, int K, int N,
    const float* __restrict__ bp1, const float* __restrict__ bp2,
    const float* __restrict__ bp3, const float* __restrict__ res,
    short* __restrict__ outb, float* __restrict__ outf, short* __restrict__ vt) {
  constexpr int MF  = BM / 32;      // m-frags per wave (8 or 4)
  constexpr int MG  = MF / 2;       // m-frags per phase
  constexpr int SA  = BM * 64;      // A slot bytes ([BM][32] bf16)
  constexpr int SB  = 16384;        // B slot bytes ([256][32] bf16)
  constexpr int CPA = BM / 128;     // A 1KB-chunks per wave per half-stage
  constexpr int CPB = 2;
  constexpr int NW  = CPA + CPB;    // in-flight loads allowed at the wait
  __shared__ char lds[4 * SA + 4 * SB];
  char* Ab = lds;
  char* Bb = lds + 4 * SA;
  int tid = threadIdx.x, lane = tid & 63, w = tid >> 6;
  int wm = w >> 2, wn = w & 3, hi = lane >> 4, lo = lane & 15;
  int bm = blockIdx.y * BM, bn = blockIdx.x * 256;

  const char* gA[CPA]; int lA[CPA];
  const char* gB[CPB]; int lB[CPB];
#pragma unroll
  for (int i = 0; i < CPA; ++i) {
    int c = w * CPA + i, r = c * 16 + (lane >> 2);
    gA[i] = (const char*)(A + (size_t)(bm + r) * K) + (((lane & 3) ^ ((r >> 1) & 3)) << 4);
    lA[i] = c * 1024;
  }
#pragma unroll
  for (int i = 0; i < CPB; ++i) {
    int c = w * CPB + i, r = c * 16 + (lane >> 2);
    gB[i] = (const char*)(Bt + (size_t)(bn + r) * K) + (((lane & 3) ^ ((r >> 1) & 3)) << 4);
    lB[i] = c * 1024;
  }
  auto stA = [&](int g) {
    char* d = Ab + (g & 3) * SA;
#pragma unroll
    for (int i = 0; i < CPA; ++i) gload16(gA[i] + (size_t)g * 64, d + lA[i]);
  };
  auto stB = [&](int g) {
    char* d = Bb + (g & 3) * SB;
#pragma unroll
    for (int i = 0; i < CPB; ++i) gload16(gB[i] + (size_t)g * 64, d + lB[i]);
  };

  int offA[MF], offB[4];
#pragma unroll
  for (int m = 0; m < MF; ++m) {
    int r = wm * (BM / 2) + m * 16 + lo;
    offA[m] = r * 64 + ((hi ^ ((r >> 1) & 3)) << 4);
  }
#pragma unroll
  for (int n = 0; n < 4; ++n) {
    int r = wn * 64 + n * 16 + lo;
    offB[n] = r * 64 + ((hi ^ ((r >> 1) & 3)) << 4);
  }

  f32x4 acc[MF][4];
#pragma unroll
  for (int m = 0; m < MF; ++m)
#pragma unroll
    for (int n = 0; n < 4; ++n) acc[m][n] = (f32x4){0.f, 0.f, 0.f, 0.f};

  stA(0); stB(0); stA(1); stB(1);
  vwait<NW>(); bar();

  int NT = K >> 6;
  auto tile = [&](int t, auto stc) {
    constexpr bool ST = decltype(stc)::value;
    char* sa0 = Ab + ((2 * t) & 3) * SA;     char* sb0 = Bb + ((2 * t) & 3) * SB;
    char* sa1 = Ab + ((2 * t + 1) & 3) * SA; char* sb1 = Bb + ((2 * t + 1) & 3) * SB;
    short8 bf[4], af[MG];
    // ---- ph0: mg0 x k0
#pragma unroll
    for (int n = 0; n < 4; ++n) bf[n] = *(const short8*)(sb0 + offB[n]);
#pragma unroll
    for (int m = 0; m < MG; ++m) af[m] = *(const short8*)(sa0 + offA[m]);
    if constexpr (ST) stA(2 * t + 2);
    bar(); __builtin_amdgcn_s_setprio(1);
#pragma unroll
    for (int m = 0; m < MG; ++m)
#pragma unroll
      for (int n = 0; n < 4; ++n)
        acc[m][n] = __builtin_amdgcn_mfma_f32_16x16x32_bf16(af[m], bf[n], acc[m][n], 0, 0, 0);
    __builtin_amdgcn_s_setprio(0); bar();
    // ---- ph1: mg1 x k0
#pragma unroll
    for (int m = 0; m < MG; ++m) af[m] = *(const short8*)(sa0 + offA[MG + m]);
    if constexpr (ST) stB(2 * t + 2);
    bar(); __builtin_amdgcn_s_setprio(1);
#pragma unroll
    for (int m = 0; m < MG; ++m)
#pragma unroll
      for (int n = 0; n < 4; ++n)
        acc[MG + m][n] = __builtin_amdgcn_mfma_f32_16x16x32_bf16(af[m], bf[n], acc[MG + m][n], 0, 0, 0);
    __builtin_amdgcn_s_setprio(0);
    if constexpr (ST) vwait<NW>(); else vwait<0>();
    bar();
    // ---- ph2: mg0 x k1
#pragma unroll
    for (int n = 0; n < 4; ++n) bf[n] = *(const short8*)(sb1 + offB[n]);
#pragma unroll
    for (int m = 0; m < MG; ++m) af[m] = *(const short8*)(sa1 + offA[m]);
    if constexpr (ST) stA(2 * t + 3);
    bar(); __builtin_amdgcn_s_setprio(1);
#pragma unroll
    for (int m = 0; m < MG; ++m)
#pragma unroll
      for (int n = 0; n < 4; ++n)
        acc[m][n] = __builtin_amdgcn_mfma_f32_16x16x32_bf16(af[m], bf[n], acc[m][n], 0, 0, 0);
    __builtin_amdgcn_s_setprio(0); bar();
    // ---- ph3: mg1 x k1
#pragma unroll
    for (int m = 0; m < MG; ++m) af[m] = *(const short8*)(sa1 + offA[MG + m]);
    if constexpr (ST) stB(2 * t + 3);
    bar(); __builtin_amdgcn_s_setprio(1);
#pragma unroll
    for (int m = 0; m < MG; ++m)
#pragma unroll
      for (int n = 0; n < 4; ++n)
        acc[MG + m][n] = __builtin_amdgcn_mfma_f32_16x16x32_bf16(af[m], bf[n], acc[MG + m][n], 0, 0, 0);
    __builtin_amdgcn_s_setprio(0);
    if constexpr (ST) vwait<NW>();
    bar();
  };

  for (int t = 0; t < NT - 1; ++t) tile(t, BoolC<true>{});
  tile(NT - 1, BoolC<false>{});

#pragma unroll
  for (int mf = 0; mf < MF; ++mf) {
#pragma unroll
    for (int nf = 0; nf < 4; ++nf) {
      int n = bn + wn * 64 + nf * 16 + lo;
#pragma unroll
      for (int r = 0; r < 4; ++r) {
        int m = bm + wm * (BM / 2) + mf * 16 + hi * 4 + r;
        float v = acc[mf][nf][r];
        if (EPI == 0) {
          float bb = (n < 2048) ? bp1[n] : (n < 4096) ? bp2[n - 2048] : bp3[n - 4096];
          v += bb;
          if (n < 2048) v *= 0.08838834764831845f;   // 1/sqrt(128) folded into Q
          outb[(size_t)m * N + n] = f2bf(v);
          if (n >= 4096) {                           // V also stored transposed
            int b_ = m >> 11, s_ = m & 2047, h_ = (n - 4096) >> 7, dk = (n - 4096) & 127;
            vt[((size_t)((b_ * 16 + h_) * 128 + dk) << 11) + s_] = f2bf(v);
          }
        } else if (EPI == 1) {
          outf[(size_t)m * N + n] = res[(size_t)m * N + n] + v + bp1[n];
        } else {
          float t = v + bp1[n];
          outb[(size_t)m * N + n] = f2bf(0.5f * t * (1.0f + erff(t * 0.70710678118654752f)));
        }
      }
    }
  }
}

// ---------------- flash attention v2: pipelined, 8 waves ----------------------
// grid (16 q-tiles, 32 b*h), block 512 = 8 waves; each wave owns 16 q-rows.
// K/V double-buffered in LDS (ring-2): stage(t+1) issued BEFORE compute(t),
// single vmcnt(0)+barrier per tile -> HBM latency hides under compute.
// Race-freedom: slot (t+1)&1 was last read during iter t-1, whose reads
// completed before iter t-1's end-barrier (values consumed by that wave's
// own MFMAs). P is per-wave-private in LDS (2KB each) -> no barrier needed.
// Fully-masked diagonal tiles skip compute per-wave (barriers still uniform).
__global__ __launch_bounds__(512, 4) void attn_kernel(
    const short* __restrict__ qkv, const short* __restrict__ vtb,
    short* __restrict__ ctx) {
  __shared__ char Kl[2][16384];               // [64 kv][128 dk] bf16, swizzled
  __shared__ char Vl[2][16384];               // [128 dk][64 kv] bf16, swizzled
  __shared__ char Pl[16384];                  // 8 x [16 q][64 kv] bf16, per-wave
  int qt = blockIdx.x, bh = blockIdx.y;
  int b = bh >> 4, h = bh & 15;
  int tid = threadIdx.x, lane = tid & 63, w = tid >> 6;   // w: 0..7
  int hi = lane >> 4, lo = lane & 15;
  int qrow0 = qt * 128 + w * 16;              // wave's first q row (within S)

  // hoist Q fragments (A-frag: row=lo, k=hi*8.. over 4 chunks of dk=32)
  short8 qf[4];
#pragma unroll
  for (int ks = 0; ks < 4; ++ks)
    qf[ks] = *(const short8*)(qkv + (size_t)(b * 2048 + qrow0 + lo) * 6144
                              + h * 128 + ks * 32 + hi * 8);

  f32x4 ao[8] = {};
  float mst[4], lst[4];
#pragma unroll
  for (int r = 0; r < 4; ++r) { mst[r] = -1e30f; lst[r] = 0.f; }

  // stage tile t into slot t&1: wave w stages K chunks 2w,2w+1 + V chunks 2w,2w+1
  auto stage = [&](int t) {
    int sl = t & 1;
#pragma unroll
    for (int i = 0; i < 2; ++i) {
      int c = 2 * w + i;
      int kr = c * 4 + (lane >> 4);           // K chunk: 4 rows x 256B
      const short* kg = qkv + (size_t)(b * 2048 + t * 64 + kr) * 6144
                            + 2048 + h * 128 + (lo ^ (kr & 7)) * 8;
      gload16(kg, Kl[sl] + c * 1024);
      int vr = c * 8 + (lane >> 3);           // V chunk: 8 rows x 128B
      const short* vg = vtb + (size_t)(bh * 128 + vr) * 2048
                            + t * 64 + ((lane & 7) ^ (vr & 7)) * 8;
      gload16(vg, Vl[sl] + c * 1024);
    }
  };

  stage(0);
  vwait<0>(); bar();

  int nt = 2 * qt + 2;                        // causal: tiles 0..2qt+1
  for (int t = 0; t < nt; ++t) {
    if (t + 1 < nt) stage(t + 1);
    const char* Ks = Kl[t & 1];
    const char* Vs = Vl[t & 1];
    int kv0 = t * 64;
    if (kv0 <= qrow0 + 15) {                  // else fully masked for this wave
      // S = Q K^T  (1x4 frags, K-loop over dk)
      f32x4 sc[4] = {};
#pragma unroll
      for (int ks = 0; ks < 4; ++ks) {
        short8 kf[4];
#pragma unroll
        for (int ni = 0; ni < 4; ++ni) {
          int r = ni * 16 + lo;
          kf[ni] = *(const short8*)(Ks + r * 256 + (((ks * 4 + hi) ^ (r & 7)) << 4));
        }
#pragma unroll
        for (int ni = 0; ni < 4; ++ni)
          sc[ni] = __builtin_amdgcn_mfma_f32_16x16x32_bf16(qf[ks], kf[ni], sc[ni], 0, 0, 0);
      }
      if (kv0 + 63 > qrow0) {                 // diagonal: elementwise causal mask
#pragma unroll
        for (int ni = 0; ni < 4; ++ni)
#pragma unroll
          for (int r = 0; r < 4; ++r)
            if (kv0 + ni * 16 + lo > qrow0 + hi * 4 + r) sc[ni][r] = -1e9f;
      }
      // online softmax (row r: 16-lane group reduce)
#pragma unroll
      for (int r = 0; r < 4; ++r) {
        float vm = fmaxf(fmaxf(sc[0][r], sc[1][r]), fmaxf(sc[2][r], sc[3][r]));
#pragma unroll
        for (int off = 8; off; off >>= 1) vm = fmaxf(vm, __shfl_xor(vm, off));
        float mn = fmaxf(mst[r], vm);
        float corr = __expf(mst[r] - mn);
        float ps = 0.f;
#pragma unroll
        for (int ni = 0; ni < 4; ++ni) {
          float p = __expf(sc[ni][r] - mn);
          sc[ni][r] = p; ps += p;
        }
#pragma unroll
        for (int off = 8; off; off >>= 1) ps += __shfl_xor(ps, off);
        lst[r] = lst[r] * corr + ps;
        mst[r] = mn;
#pragma unroll
        for (int ni = 0; ni < 8; ++ni) ao[ni][r] *= corr;
      }
      // P -> per-wave LDS (swizzled)
#pragma unroll
      for (int ni = 0; ni < 4; ++ni)
#pragma unroll
        for (int r = 0; r < 4; ++r) {
          int rl = hi * 4 + r;
          int byte = (rl * 128 + (ni * 16 + lo) * 2) ^ ((rl & 7) << 4);
          *(short*)(Pl + w * 2048 + byte) = f2bf(sc[ni][r]);
        }
      // O += P V
#pragma unroll
      for (int ks = 0; ks < 2; ++ks) {
        short8 pf = *(const short8*)(Pl + w * 2048 + lo * 128
                                     + (((ks * 4 + hi) ^ (lo & 7)) << 4));
#pragma unroll
        for (int ni = 0; ni < 8; ++ni) {
          int r = ni * 16 + lo;
          short8 vf = *(const short8*)(Vs + r * 128 + (((ks * 4 + hi) ^ (r & 7)) << 4));
          ao[ni] = __builtin_amdgcn_mfma_f32_16x16x32_bf16(pf, vf, ao[ni], 0, 0, 0);
        }
      }
    }
    vwait<0>(); bar();                        // t+1 landed; slot t&1 free next iter
  }

  // normalize + store ctx bf16 [4096][2048]
#pragma unroll
  for (int r = 0; r < 4; ++r) {
    float inv = 1.0f / lst[r];
    int m = b * 2048 + qrow0 + hi * 4 + r;
#pragma unroll
    for (int ni = 0; ni < 8; ++ni)
      ctx[(size_t)m * 2048 + h * 128 + ni * 16 + lo] = f2bf(ao[ni][r] * inv);
  }
}

// -----------------------------------------------------------------------------
extern "C" void kernel_launch(void* const* d_in, const int* in_sizes, int n_in,
                              void* d_out, int out_size, void* d_ws, size_t ws_size,
                              hipStream_t stream) {
  const float* src = (const float*)d_in[0];
  const float* Wq = (const float*)d_in[2];  const float* bq = (const float*)d_in[3];
  const float* Wk = (const float*)d_in[4];  const float* bk = (const float*)d_in[5];
  const float* Wv = (const float*)d_in[6];  const float* bv = (const float*)d_in[7];
  const float* Wo = (const float*)d_in[8];  const float* bo = (const float*)d_in[9];
  const float* g1 = (const float*)d_in[10]; const float* be1 = (const float*)d_in[11];
  const float* g2 = (const float*)d_in[12]; const float* be2 = (const float*)d_in[13];
  const float* W1 = (const float*)d_in[14]; const float* b1 = (const float*)d_in[15];
  const float* W2 = (const float*)d_in[16]; const float* b2 = (const float*)d_in[17];

  // workspace layout (bytes), total 167,772,160:
  //   [0        ) x_ln   bf16 [4096][2048]
  //   [16777216 ) qkv    bf16 [4096][6144]   (hb aliases qkv+vt)
  //   [67108864 ) vt     bf16 [32][128][2048]
  //   [83886080 ) ctx    bf16 [4096][2048]
  //   [100663296) xbuf   f32  [4096][2048]
  //   [134217728) wt     bf16 (reused)
  char* ws = (char*)d_ws;
  short* x_ln = (short*)(ws);
  short* qkvb = (short*)(ws + 16777216);
  short* vtb  = (short*)(ws + 67108864);
  short* ctxb = (short*)(ws + 83886080);
  float* xbuf = (float*)(ws + 100663296);
  short* wt   = (short*)(ws + 134217728);
  short* hb   = (short*)(ws + 16777216);

  dim3 tb(64, 4);

  wt_kernel<<<dim3(32, 32), tb, 0, stream>>>(Wq, wt,                2048, 2048);
  wt_kernel<<<dim3(32, 32), tb, 0, stream>>>(Wk, wt + 2048 * 2048,  2048, 2048);
  wt_kernel<<<dim3(32, 32), tb, 0, stream>>>(Wv, wt + 4096 * 2048,  2048, 2048);
  ln_kernel<<<4096, 256, 0, stream>>>(src, g1, be1, x_ln);
  gemm8_kernel<256, 0><<<dim3(24, 16), 512, 0, stream>>>(
      x_ln, wt, 2048, 6144, bq, bk, bv, nullptr, qkvb, nullptr, vtb);
  attn_kernel<<<dim3(16, 32), 512, 0, stream>>>(qkvb, vtb, ctxb);
  wt_kernel<<<dim3(32, 32), tb, 0, stream>>>(Wo, wt, 2048, 2048);
  gemm8_kernel<128, 1><<<dim3(8, 32), 512, 0, stream>>>(
      ctxb, wt, 2048, 2048, bo, nullptr, nullptr, src, nullptr, xbuf, nullptr);
  ln_kernel<<<4096, 256, 0, stream>>>(xbuf, g2, be2, x_ln);
  wt_kernel<<<dim3(32, 128), tb, 0, stream>>>(W1, wt, 2048, 8192);
  gemm8_kernel<256, 2><<<dim3(32, 16), 512, 0, stream>>>(
      x_ln, wt, 2048, 8192, b1, nullptr, nullptr, nullptr, hb, nullptr, nullptr);
  wt_kernel<<<dim3(128, 32), tb, 0, stream>>>(W2, wt, 8192, 2048);
  gemm8_kernel<128, 1><<<dim3(8, 32), 512, 0, stream>>>(
      hb, wt, 8192, 2048, b2, nullptr, nullptr, xbuf, nullptr, (float*)d_out, nullptr);

  (void)in_sizes; (void)n_in; (void)out_size; (void)ws_size;
}